// Round 5
// baseline (210.268 us; speedup 1.0000x reference)
//
#include <hip/hip_runtime.h>
#include <math.h>

#define BB 8
#define SS 1024
#define DD 768
#define HH 12
#define DHH 64
#define BSS (BB*SS)          // 8192
#define NQKV 2304            // stacked Q|K|V output columns
#define NT 24                // 768 / BK(=32) K-tiles

typedef _Float16 half8 __attribute__((ext_vector_type(8)));
typedef _Float16 half4 __attribute__((ext_vector_type(4)));
typedef float    f32x4 __attribute__((ext_vector_type(4)));

// Async global->LDS DMA, 16 B/lane. LDS dest = wave-uniform base + lane*16.
__device__ __forceinline__ void glds16(const _Float16* g, _Float16* l)
{
    __builtin_amdgcn_global_load_lds(
        (const __attribute__((address_space(1))) uint32_t*)(g),
        (__attribute__((address_space(3))) uint32_t*)(l),
        16, 0, 0);
}

#define WAITV(N) asm volatile("s_waitcnt vmcnt(" #N ")" ::: "memory")

// ---------------------------------------------------------------------------
// prep (unchanged)
// ---------------------------------------------------------------------------
__global__ __launch_bounds__(256)
void prep(const float* __restrict__ x, _Float16* __restrict__ xh,
          const float* __restrict__ Wq, const float* __restrict__ Wk,
          const float* __restrict__ Wv, const float* __restrict__ Wo,
          _Float16* __restrict__ Wt, _Float16* __restrict__ Wot)
{
    const int blk = blockIdx.x;
    const int tid = threadIdx.x;

    if (blk < 3072) {                    // ---- cast x -> f16 ----
        int i = blk * 256 + tid;
        const float4* xp = (const float4*)x + (size_t)i * 2;
        float4 u = xp[0], v = xp[1];
        half8 h = { (_Float16)u.x, (_Float16)u.y, (_Float16)u.z, (_Float16)u.w,
                    (_Float16)v.x, (_Float16)v.y, (_Float16)v.z, (_Float16)v.w };
        ((half8*)xh)[i] = h;
        return;
    }

    // ---- weight transpose: 576 tiles = (12 d0) x (12 n) x (4 z) ----
    __shared__ float T[64][65];
    const int t  = blk - 3072;
    const int z  = t / 144;              // 0..3
    const int r_ = t - z * 144;
    const int d0 = (r_ / 12) * 64;
    const int n_outer = r_ % 12;

    const float* src;
    _Float16* dst;
    int base_mul, row_stride;
    if (z < 3) {
        src = (z == 0) ? Wq : (z == 1) ? Wk : Wv;
        dst = Wt + (size_t)z * DD * DD;
        base_mul = DD * DHH; row_stride = DHH;
    } else {
        src = Wo; dst = Wot;
        base_mul = 64; row_stride = DD;
    }

    const size_t base = (size_t)n_outer * base_mul;
    {
        int dl = tid >> 2, c0 = (tid & 3) * 16;
        const float* p = src + base + (size_t)(d0 + dl) * row_stride + c0;
#pragma unroll
        for (int m = 0; m < 4; ++m) {
            float4 f = *(const float4*)(p + m * 4);
            T[dl][c0 + m*4 + 0] = f.x;
            T[dl][c0 + m*4 + 1] = f.y;
            T[dl][c0 + m*4 + 2] = f.z;
            T[dl][c0 + m*4 + 3] = f.w;
        }
    }
    __syncthreads();
    {
        int e = tid >> 2, c = tid & 3;
        half8 lo, hi;
#pragma unroll
        for (int i = 0; i < 8; ++i) {
            lo[i] = (_Float16)T[c*16 + i][e];
            hi[i] = (_Float16)T[c*16 + 8 + i][e];
        }
        _Float16* q = dst + ((size_t)n_outer * 64 + e) * DD + d0 + c * 16;
        *(half8*)q = lo;
        *(half8*)(q + 8) = hi;
    }
}

// ---------------------------------------------------------------------------
// Stacked QKV GEMM, round-13: r3's exact-256 geometry (256x288 tile, 32x8
// grid = 1 block/CU, zero dispatch tail) x r1's proven inner schedule
// (2-phase interleave per K-tile: {A+B0-3 frag reads | A-stage | 16 MFMA} +
// {B4-8 reads | B-stage | 20 MFMA}, ONE counted-vmcnt gate per tile at
// lead-2, quad-buffer, #pragma unroll 4 + hand-peeled tail, T2 swizzle,
// T5 setprio).  8 waves, wave-tile 64x144 (acc[4][9]).  LDS 136 KB.
// ---------------------------------------------------------------------------
__global__ __launch_bounds__(512, 2)
void gemm_qkv_v5(const _Float16* __restrict__ Xh, const _Float16* __restrict__ Wt,
                 const float* __restrict__ bq, const float* __restrict__ bk,
                 const float* __restrict__ bv,
                 _Float16* __restrict__ qo, _Float16* __restrict__ ko,
                 _Float16* __restrict__ vto)
{
    __shared__ _Float16 Ab[4][256][32];   // 64 KB
    __shared__ _Float16 Bb[4][288][32];   // 72 KB

    const int bid = blockIdx.x;          // 0..255
    const int c8  = bid & 7;             // XCD
    const int g   = bid >> 3;            // 0..31
    const int m_t = c8 * 4 + (g >> 3);   // 0..31
    const int n_t = g & 7;               // 0..7
    const int m0 = m_t * 256;
    const int n0 = n_t * 288;

    const int tid  = threadIdx.x;
    const int wave = tid >> 6;           // 0..7
    const int lane = tid & 63;
    const int l16  = tid & 15;
    const int quad = (tid >> 4) & 3;
    const int wy = wave >> 1;            // 0..3 : wave tile 64x144
    const int wx = wave & 1;             // 0..1

    const int scol = ((lane & 3) ^ ((lane >> 3) & 3)) * 8;
    const int fcol = (quad ^ ((l16 >> 1) & 3)) * 8;

    const bool big = (wave == 0) || (wave == 4);   // 5 loads/tile vs 4

    const _Float16* apA = Xh + (size_t)(m0 + 32 * wave + (lane >> 2)) * DD + scol;
    const _Float16* bpB = Wt + (size_t)(n0 + 32 * wave + (lane >> 2)) * DD + scol;
    const _Float16* bpX = Wt + (size_t)(n0 + 256 + ((wave & 4) << 2) + (lane >> 2)) * DD + scol;
    const int xrow = 256 + ((wave & 4) << 2);

#define STAGE_A(buf, kt) do {                                             \
        glds16(apA + (kt) * 32,           &Ab[buf][32 * wave][0]);        \
        glds16(apA + (kt) * 32 + 16 * DD, &Ab[buf][32 * wave + 16][0]);   \
    } while (0)
#define STAGE_B(buf, kt) do {                                             \
        glds16(bpB + (kt) * 32,           &Bb[buf][32 * wave][0]);        \
        glds16(bpB + (kt) * 32 + 16 * DD, &Bb[buf][32 * wave + 16][0]);   \
        if (big) glds16(bpX + (kt) * 32,  &Bb[buf][xrow][0]);             \
    } while (0)

    f32x4 acc[4][9];
#pragma unroll
    for (int i = 0; i < 4; ++i)
#pragma unroll
        for (int j = 0; j < 9; ++j) acc[i][j] = (f32x4){0.f, 0.f, 0.f, 0.f};

    // Tile body: r1's 2-phase interleave.  SA/SB = staging statements.
#define QTILE(buf, SA, SB)                                                  \
    {                                                                       \
        half8 a[4], bf[9];                                                  \
        _Pragma("unroll")                                                   \
        for (int i = 0; i < 4; ++i)                                         \
            a[i] = *(const half8*)&Ab[buf][wy * 64 + i * 16 + l16][fcol];   \
        _Pragma("unroll")                                                   \
        for (int j = 0; j < 4; ++j)                                         \
            bf[j] = *(const half8*)&Bb[buf][wx * 144 + j * 16 + l16][fcol]; \
        SA;                                                                 \
        __builtin_amdgcn_s_setprio(1);                                      \
        _Pragma("unroll")                                                   \
        for (int i = 0; i < 4; ++i)                                         \
            _Pragma("unroll")                                               \
            for (int j = 0; j < 4; ++j)                                     \
                acc[i][j] = __builtin_amdgcn_mfma_f32_16x16x32_f16(a[i], bf[j], acc[i][j], 0, 0, 0); \
        __builtin_amdgcn_s_setprio(0);                                      \
        _Pragma("unroll")                                                   \
        for (int j = 4; j < 9; ++j)                                         \
            bf[j] = *(const half8*)&Bb[buf][wx * 144 + j * 16 + l16][fcol]; \
        SB;                                                                 \
        __builtin_amdgcn_s_setprio(1);                                      \
        _Pragma("unroll")                                                   \
        for (int i = 0; i < 4; ++i)                                         \
            _Pragma("unroll")                                               \
            for (int j = 4; j < 9; ++j)                                     \
                acc[i][j] = __builtin_amdgcn_mfma_f32_16x16x32_f16(a[i], bf[j], acc[i][j], 0, 0, 0); \
        __builtin_amdgcn_s_setprio(0);                                      \
    }

#define GATE_MAIN do { if (big) WAITV(10); else WAITV(8);                   \
                       __builtin_amdgcn_s_barrier(); } while (0)

    // ---- prologue: stage tiles 0,1,2 ----
    STAGE_A(0, 0); STAGE_B(0, 0);
    STAGE_A(1, 1); STAGE_B(1, 1);
    STAGE_A(2, 2); STAGE_B(2, 2);
    GATE_MAIN;                           // tile 0 resident; tiles 1,2 in flight

    // ---- main loop: kt = 0..19, stage kt+3 (lead-2 at the gate) ----
#pragma unroll 4
    for (int kt = 0; kt < 20; ++kt) {
        const int buf = kt & 3;
        const int nb  = (kt + 3) & 3;
        QTILE(buf, STAGE_A(nb, kt + 3), STAGE_B(nb, kt + 3));
        GATE_MAIN;
    }
    // ---- peeled tail ----
    QTILE(0, STAGE_A(3, 23), STAGE_B(3, 23));   // kt = 20
    GATE_MAIN;
    QTILE(1, , );                               // kt = 21
    if (big) WAITV(5); else WAITV(4);
    __builtin_amdgcn_s_barrier();
    QTILE(2, , );                               // kt = 22
    WAITV(0);
    __builtin_amdgcn_s_barrier();
    QTILE(3, , );                               // kt = 23

#undef QTILE
#undef GATE_MAIN
#undef STAGE_A
#undef STAGE_B

    // ---- epilogue: per-fragment Q|K|V resolution (boundaries 16-aligned) ----
    float bvv[9]; int hh9[9], ee9[9], ws9[9];
#pragma unroll
    for (int j = 0; j < 9; ++j) {
        int nl = n0 + wx * 144 + j * 16 + l16;   // 0..2303
        int ws = nl / 768;                        // 0=Q 1=K 2=V (frag-uniform)
        int nloc = nl - ws * 768;
        const float* bp_ = (ws == 0) ? bq : (ws == 1) ? bk : bv;
        bvv[j] = bp_[nloc];
        hh9[j] = nloc >> 6;
        ee9[j] = nloc & 63;
        ws9[j] = ws;
    }

#pragma unroll
    for (int i = 0; i < 4; ++i) {
#pragma unroll
        for (int r = 0; r < 4; ++r) {
            int row = m0 + wy * 64 + i * 16 + quad * 4 + r;
            int b_ = row >> 10;
            int s  = row & (SS - 1);
#pragma unroll
            for (int j = 0; j < 9; ++j) {
                float val = acc[i][j][r] + bvv[j];
                if (ws9[j] == 0)
                    qo[((size_t)(b_ * HH + hh9[j]) * SS + s) * DHH + ee9[j]] = (_Float16)(val * 0.125f);
                else if (ws9[j] == 1)
                    ko[((size_t)(b_ * HH + hh9[j]) * SS + s) * DHH + ee9[j]] = (_Float16)val;
                else
                    vto[((size_t)(b_ * HH + hh9[j]) * DHH + ee9[j]) * SS + s] = (_Float16)val;
            }
        }
    }
}

// ---------------------------------------------------------------------------
// Out-projection GEMM (unchanged from round 12): 128x64 tile, tri-buffer +
// counted vmcnt(3) gate, wave-tile 64x32, T2 swizzle.
// ---------------------------------------------------------------------------
__global__ __launch_bounds__(256)
void gemm_out_f16(const _Float16* __restrict__ Ah, const _Float16* __restrict__ Bt,
                  const float* __restrict__ bias, float* __restrict__ out)
{
    __shared__ _Float16 Ash[3][128][32];
    __shared__ _Float16 Bsh[3][64][32];

    const int m0 = blockIdx.x * 128;
    const int n0 = blockIdx.y * 64;
    const int tid  = threadIdx.x;
    const int wave = tid >> 6;
    const int lane = tid & 63;
    const int l16  = tid & 15;
    const int quad = (tid >> 4) & 3;
    const int wy = wave >> 1;
    const int wx = wave & 1;

    const int scol = ((lane & 3) ^ ((lane >> 3) & 3)) * 8;
    const int fcol = (quad ^ ((l16 >> 1) & 3)) * 8;

    const _Float16* ap = Ah + (size_t)(m0 + 32 * wave + (lane >> 2)) * DD + scol;
    const _Float16* bp = Bt + (size_t)(n0 + 16 * wave + (lane >> 2)) * DD + scol;

#define OSTAGE(buf, kt) do {                                              \
        glds16(ap + (kt) * 32,           &Ash[buf][32 * wave][0]);        \
        glds16(ap + (kt) * 32 + 16 * DD, &Ash[buf][32 * wave + 16][0]);   \
        glds16(bp + (kt) * 32,           &Bsh[buf][16 * wave][0]);        \
    } while (0)

    f32x4 acc[4][2];
#pragma unroll
    for (int i = 0; i < 4; ++i)
#pragma unroll
        for (int j = 0; j < 2; ++j) acc[i][j] = (f32x4){0.f, 0.f, 0.f, 0.f};

#define OCOMPUTE(buf)                                                       \
    {                                                                       \
        half8 a[4], bf[2];                                                  \
        _Pragma("unroll")                                                   \
        for (int i = 0; i < 4; ++i)                                         \
            a[i] = *(const half8*)&Ash[buf][wy * 64 + i * 16 + l16][fcol];  \
        _Pragma("unroll")                                                   \
        for (int j = 0; j < 2; ++j)                                         \
            bf[j] = *(const half8*)&Bsh[buf][wx * 32 + j * 16 + l16][fcol]; \
        __builtin_amdgcn_s_setprio(1);                                      \
        _Pragma("unroll")                                                   \
        for (int i = 0; i < 4; ++i)                                         \
            _Pragma("unroll")                                               \
            for (int j = 0; j < 2; ++j)                                     \
                acc[i][j] = __builtin_amdgcn_mfma_f32_16x16x32_f16(a[i], bf[j], acc[i][j], 0, 0, 0); \
        __builtin_amdgcn_s_setprio(0);                                      \
    }

    OSTAGE(0, 0); OSTAGE(1, 1);
    WAITV(3);
    __builtin_amdgcn_s_barrier();

    int cur = 0;
    for (int kt = 0; kt < NT - 2; ++kt) {           // 0..21
        const int stg = cur ? cur - 1 : 2;
        OSTAGE(stg, kt + 2);
        OCOMPUTE(cur);
        WAITV(3);
        __builtin_amdgcn_s_barrier();
        cur = (cur == 2) ? 0 : cur + 1;
    }
    OCOMPUTE(1);
    WAITV(0);
    __builtin_amdgcn_s_barrier();
    OCOMPUTE(2);

#undef OCOMPUTE
#undef OSTAGE

#pragma unroll
    for (int i = 0; i < 4; ++i) {
#pragma unroll
        for (int r = 0; r < 4; ++r) {
            int row = m0 + wy * 64 + i * 16 + quad * 4 + r;
#pragma unroll
            for (int j = 0; j < 2; ++j) {
                int col = n0 + wx * 32 + j * 16 + l16;
                out[(size_t)row * DD + col] = acc[i][j][r] + bias[col];
            }
        }
    }
}

// ---------------------------------------------------------------------------
// Flash attention (unchanged).
// ---------------------------------------------------------------------------
__global__ __launch_bounds__(512)
void attn_f16(const _Float16* __restrict__ qh, const _Float16* __restrict__ kh,
              const _Float16* __restrict__ vt, _Float16* __restrict__ ctxh)
{
    const int bh  = blockIdx.x;
    const int q0  = blockIdx.y * 128;
    const int tid = threadIdx.x;
    const int wave = tid >> 6;          // 0..7
    const int lane = tid & 63;
    const int l16  = tid & 15;
    const int quad = (tid >> 4) & 3;

    __shared__ _Float16 Ks[2][2][64][32];   // [dbuf][d-chunk][key][32]
    __shared__ _Float16 Vt[2][2][64][32];   // [dbuf][kk-chunk][e][32]
    __shared__ _Float16 Pt[8][16][72];      // per-wave P [q][kk]

    const int scol = ((lane & 3) ^ ((lane >> 3) & 3)) * 8;
    const int fcol = (quad ^ ((l16 >> 1) & 3)) * 8;

    // ---- Q frags: direct global (once) ----
    const _Float16* qrow = qh + ((size_t)bh * SS + q0 + wave * 16 + l16) * DHH;
    const half8 qlo = *(const half8*)(qrow + quad * 8);
    const half8 qhi = *(const half8*)(qrow + 32 + quad * 8);

    // ---- DMA sources: sub-wave sw covers 16 rows of its matrix ----
    const int sw = wave & 3;
    const _Float16* kp = kh + ((size_t)bh * SS + 16 * sw + (lane >> 2)) * DHH + scol;
    const _Float16* vp = vt + ((size_t)bh * DHH + 16 * sw + (lane >> 2)) * SS + scol;

    f32x4 o[4];
    float lacc = 0.f;
#pragma unroll
    for (int j = 0; j < 4; ++j) o[j] = (f32x4){0.f, 0.f, 0.f, 0.f};

    // ---- prefetch tile 0 -> buffer 0 ----
    if (wave < 4) {
        glds16(kp,      &Ks[0][0][16 * sw][0]);
        glds16(kp + 32, &Ks[0][1][16 * sw][0]);
    } else {
        glds16(vp,      &Vt[0][0][16 * sw][0]);
        glds16(vp + 32, &Vt[0][1][16 * sw][0]);
    }

    int cur = 0;
    for (int kt = 0; kt < SS; kt += 64) {
        __syncthreads();                 // buf[cur] ready; buf[cur^1] reads done
        if (kt + 64 < SS) {
            if (wave < 4) {
                glds16(kp + (size_t)(kt + 64) * DHH,      &Ks[cur ^ 1][0][16 * sw][0]);
                glds16(kp + (size_t)(kt + 64) * DHH + 32, &Ks[cur ^ 1][1][16 * sw][0]);
            } else {
                glds16(vp + kt + 64,      &Vt[cur ^ 1][0][16 * sw][0]);
                glds16(vp + kt + 64 + 32, &Vt[cur ^ 1][1][16 * sw][0]);
            }
        }

        // ---- S^T = K·Q^T per 16-kk tile; exp; vectorized P write ----
#pragma unroll
        for (int f = 0; f < 4; ++f) {
            half8 klo = *(const half8*)&Ks[cur][0][f * 16 + l16][fcol];
            half8 khi = *(const half8*)&Ks[cur][1][f * 16 + l16][fcol];
            f32x4 z = (f32x4){0.f, 0.f, 0.f, 0.f};
            z = __builtin_amdgcn_mfma_f32_16x16x32_f16(klo, qlo, z, 0, 0, 0);
            z = __builtin_amdgcn_mfma_f32_16x16x32_f16(khi, qhi, z, 0, 0, 0);
            half4 pk;
#pragma unroll
            for (int r = 0; r < 4; ++r) {
                float p = __expf(z[r]);
                lacc += p;
                pk[r] = (_Float16)p;
            }
            *(half4*)&Pt[wave][l16][f * 16 + quad * 4] = pk;
        }

        // ---- P A-frags (same-wave LDS round trip, in-order DS) ----
        half8 pl = *(const half8*)&Pt[wave][l16][quad * 8];
        half8 ph = *(const half8*)&Pt[wave][l16][32 + quad * 8];

        // ---- PV ----
#pragma unroll
        for (int j = 0; j < 4; ++j) {
            half8 vlo = *(const half8*)&Vt[cur][0][j * 16 + l16][fcol];
            half8 vhi = *(const half8*)&Vt[cur][1][j * 16 + l16][fcol];
            o[j] = __builtin_amdgcn_mfma_f32_16x16x32_f16(pl, vlo, o[j], 0, 0, 0);
            o[j] = __builtin_amdgcn_mfma_f32_16x16x32_f16(ph, vhi, o[j], 0, 0, 0);
        }
        cur ^= 1;
    }

    // ---- l: sum quad partials (same q = l16 across quads) ----
    float lr = lacc;
    lr += __shfl_xor(lr, 16);
    lr += __shfl_xor(lr, 32);

    const int b_ = bh / HH;
    const int h_ = bh % HH;
#pragma unroll
    for (int r = 0; r < 4; ++r) {
        float invl = 1.f / __shfl(lr, quad * 4 + r, 16);
        int s_ = q0 + wave * 16 + quad * 4 + r;
        _Float16* orow = ctxh + ((size_t)(b_ * SS + s_)) * DD + h_ * DHH;
#pragma unroll
        for (int j = 0; j < 4; ++j)
            orow[j * 16 + l16] = (_Float16)(o[j][r] * invl);
    }
}

// ---------------------------------------------------------------------------
extern "C" void kernel_launch(void* const* d_in, const int* in_sizes, int n_in,
                              void* d_out, int out_size, void* d_ws, size_t ws_size,
                              hipStream_t stream)
{
    const float* x  = (const float*)d_in[0];
    const float* Wq = (const float*)d_in[1];
    const float* bq = (const float*)d_in[2];
    const float* Wk = (const float*)d_in[3];
    const float* bk = (const float*)d_in[4];
    const float* Wv = (const float*)d_in[5];
    const float* bv = (const float*)d_in[6];
    const float* Wo = (const float*)d_in[7];
    const float* bo = (const float*)d_in[8];
    float* out = (float*)d_out;

    const size_t xe = (size_t)BSS * DD;          // 6,291,456
    const size_t we = (size_t)DD * DD;           // 589,824
    _Float16* Xh   = (_Float16*)d_ws;
    _Float16* Wt   = Xh  + xe;                   // [2304][768]
    _Float16* Wot  = Wt  + (size_t)3 * we;
    _Float16* qhb  = Wot + we;
    _Float16* khb  = qhb + xe;
    _Float16* vtb  = khb + xe;                   // [bh][e][s]
    _Float16* ctxh = vtb + xe;

    prep<<<3072 + 576, 256, 0, stream>>>(x, Xh, Wq, Wk, Wv, Wo, Wt, Wot);

    gemm_qkv_v5<<<(BSS / 256) * (NQKV / 288), 512, 0, stream>>>(
        Xh, Wt, bq, bk, bv, qhb, khb, vtb);

    dim3 ag(BB * HH, SS / 128);      // (96, 8) = 768 blocks
    attn_f16<<<ag, 512, 0, stream>>>(qhb, khb, vtb, ctxh);

    dim3 gg(BSS / 128, DD / 64);     // (64, 12) = 768 blocks
    gemm_out_f16<<<gg, 256, 0, stream>>>(ctxh, Wot, bo, out);
}